// Round 3
// baseline (11195.135 us; speedup 1.0000x reference)
//
#include <hip/hip_runtime.h>

typedef __attribute__((ext_vector_type(8))) short bf16x8;
typedef __attribute__((ext_vector_type(4))) float f32x4;

#define T_N 512
#define B_ALL 64
#define I_N 512
#define H_N 1024
#define O_N 512
#define NMEM 16          // blocks per cluster
#define NTHR 512
#define COLS_H 64        // h-cols per block
#define COLS_FC 32       // out-cols per block
#define KW 192           // recurrence K-slice per wave (8 waves * 192 = 1536)
#define KWFC 128         // FC K-slice per wave (8 * 128 = 1024)
#define AP_STRIDE 1544   // A-panel row stride in elements (1536 + 8 pad -> 2-way banks)

__device__ __forceinline__ unsigned short f2bf(float f) {
  unsigned int u = __float_as_uint(f);
  u += 0x7fffu + ((u >> 16) & 1u);
  return (unsigned short)(u >> 16);
}
__device__ __forceinline__ bf16x8 cvt8f(const float* __restrict__ p) {
  float4 a = *(const float4*)p;
  float4 b = *(const float4*)(p + 4);
  bf16x8 r;
  r[0] = (short)f2bf(a.x); r[1] = (short)f2bf(a.y);
  r[2] = (short)f2bf(a.z); r[3] = (short)f2bf(a.w);
  r[4] = (short)f2bf(b.x); r[5] = (short)f2bf(b.y);
  r[6] = (short)f2bf(b.z); r[7] = (short)f2bf(b.w);
  return r;
}

// Fused RNN: per step t, pre = [h_{t-1} | x_t] @ [Whh; Wih]^T + (bih+bhh); h_t = tanh(pre)
// FC(t-1) = h_{t-1} @ Wfc^T + bfc computed from the same staged panel.
// Grid: 64 blocks (4 clusters x 16 members) x 512 threads (8 waves).
// Weights persistent in VGPRs; A-panel staged in LDS; split-K reduce via LDS;
// 16-wide per-cluster flag barrier; hx double-buffered.
// OUTPUTS ARE FLOAT32 (reference output dtype). Internal h exchange is bf16.
__global__ __launch_bounds__(NTHR, 2) void rnn_fused(
    const float* __restrict__ x, const float* __restrict__ hidden,
    const float* __restrict__ Wih, const float* __restrict__ Whh,
    const float* __restrict__ bih, const float* __restrict__ bhh,
    const float* __restrict__ Wfc, const float* __restrict__ bfc,
    float* __restrict__ out, float* __restrict__ hlast,
    unsigned short* __restrict__ hx, unsigned int* __restrict__ flags)
{
  __shared__ __align__(16) unsigned short Apan[16 * AP_STRIDE];  // 49408 B
  __shared__ __align__(16) float R [8 * COLS_H  * 20];           // 40960 B
  __shared__ __align__(16) float R2[8 * COLS_FC * 20];           // 20480 B

  const int tid = threadIdx.x;
  const int l = tid & 63, w = tid >> 6;
  const int bid = blockIdx.x;
  const int c = bid & 3;        // cluster (batch group)
  const int m = bid >> 2;       // member 0..15
  const int b0 = c * 16;
  const int cbh = m * COLS_H;
  const int cbfc = m * COLS_FC;
  unsigned short* hx0 = hx + (size_t)c * 2 * 16 * H_N;  // [2][16][1024] bf16
  unsigned int* flg = flags + c * 64;

  // ---------------- persistent weight fragments (load once) ----------------
  // Recurrence B: wave w covers k in [192w, 192w+192) of K=1536 ([Whh | Wih])
  bf16x8 Bh[6][4];
  {
    const int kb0 = w * KW + ((l >> 4) << 3);
#pragma unroll
    for (int kst = 0; kst < 6; ++kst) {
      const int k = kb0 + kst * 32;
#pragma unroll
      for (int f = 0; f < 4; ++f) {
        const int col = cbh + f * 16 + (l & 15);
        const float* src = (k < H_N) ? (Whh + (size_t)col * H_N + k)
                                     : (Wih + (size_t)col * I_N + (k - H_N));
        Bh[kst][f] = cvt8f(src);
      }
    }
  }
  // FC B: wave w covers k in [128w, 128w+128) of K=1024
  bf16x8 Bf[4][2];
  {
    const int kb0 = w * KWFC + ((l >> 4) << 3);
#pragma unroll
    for (int kst = 0; kst < 4; ++kst)
#pragma unroll
      for (int f = 0; f < 2; ++f) {
        const int col = cbfc + f * 16 + (l & 15);
        Bf[kst][f] = cvt8f(Wfc + (size_t)col * H_N + kb0 + kst * 32);
      }
  }
  // reduce-lane constants
  const int hr_col = 8 * w + (l & 7);                 // local h-col this lane reduces
  const float pb = bih[cbh + hr_col] + bhh[cbh + hr_col];
  const int fc_row = l >> 2;
  const int fc_col = 4 * w + (l & 3);
  const float bfv = bfc[cbfc + fc_col];

  // x prefetch for t=0 (each thread: 2 chunks of 8)
  bf16x8 xr0, xr1;
  {
    const int q0 = tid, q1 = 512 + tid;
    xr0 = cvt8f(x + (size_t)(b0 + (q0 >> 6)) * I_N + ((q0 & 63) << 3));
    xr1 = cvt8f(x + (size_t)(b0 + (q1 >> 6)) * I_N + ((q1 & 63) << 3));
  }

  for (int t = 0; t <= T_N; ++t) {
    const bool doH = (t < T_N);

    // ---- stage A panel: [h_{t-1} (bf16, or hidden fp32 at t=0) | x_t] ----
    if (doH) {
      const int q0 = tid, q1 = 512 + tid;
      *(bf16x8*)(Apan + (q0 >> 6) * AP_STRIDE + H_N + ((q0 & 63) << 3)) = xr0;
      *(bf16x8*)(Apan + (q1 >> 6) * AP_STRIDE + H_N + ((q1 & 63) << 3)) = xr1;
    }
    {
      const unsigned short* hsrc = hx0 + (size_t)((t + 1) & 1) * 16 * H_N;
#pragma unroll
      for (int i = 0; i < 4; ++i) {
        const int q = i * 512 + tid;
        const int row = q >> 7, hc8 = (q & 127) << 3;
        bf16x8 v;
        if (t == 0) v = cvt8f(hidden + (size_t)(b0 + row) * H_N + hc8);
        else        v = *(const bf16x8*)(hsrc + (size_t)row * H_N + hc8);
        *(bf16x8*)(Apan + row * AP_STRIDE + hc8) = v;
      }
    }
    // prefetch x for step t+1 (independent of the barrier)
    if (t + 1 < T_N) {
      const int q0 = tid, q1 = 512 + tid;
      xr0 = cvt8f(x + (size_t)((t + 1) * 64 + b0 + (q0 >> 6)) * I_N + ((q0 & 63) << 3));
      xr1 = cvt8f(x + (size_t)((t + 1) * 64 + b0 + (q1 >> 6)) * I_N + ((q1 & 63) << 3));
    }
    __syncthreads();  // S1: panel staged

    // ---- FC(t-1) MFMA (reads h-part of panel) ----
    if (t > 0) {
      f32x4 afc[2] = {};
      const int abase = (l & 15) * AP_STRIDE + w * KWFC + ((l >> 4) << 3);
#pragma unroll
      for (int kst = 0; kst < 4; ++kst) {
        bf16x8 a = *(const bf16x8*)(Apan + abase + kst * 32);
        afc[0] = __builtin_amdgcn_mfma_f32_16x16x32_bf16(a, Bf[kst][0], afc[0], 0, 0, 0);
        afc[1] = __builtin_amdgcn_mfma_f32_16x16x32_bf16(a, Bf[kst][1], afc[1], 0, 0, 0);
      }
#pragma unroll
      for (int f = 0; f < 2; ++f) {
        const int col = f * 16 + (l & 15);
        *(f32x4*)(R2 + (size_t)(w * COLS_FC + col) * 20 + ((l >> 4) << 2)) = afc[f];
      }
    }
    // ---- recurrence MFMA (K=1536 concat) ----
    if (doH) {
      f32x4 acc[4] = {};
      const int abase = (l & 15) * AP_STRIDE + w * KW + ((l >> 4) << 3);
#pragma unroll
      for (int kst = 0; kst < 6; ++kst) {
        bf16x8 a = *(const bf16x8*)(Apan + abase + kst * 32);
#pragma unroll
        for (int f = 0; f < 4; ++f)
          acc[f] = __builtin_amdgcn_mfma_f32_16x16x32_bf16(a, Bh[kst][f], acc[f], 0, 0, 0);
      }
#pragma unroll
      for (int f = 0; f < 4; ++f) {
        const int col = f * 16 + (l & 15);
        *(f32x4*)(R + (size_t)(w * COLS_H + col) * 20 + ((l >> 4) << 2)) = acc[f];
      }
    }
    __syncthreads();  // S2: partials in LDS

    // ---- FC reduce + store out(t-1) as FP32 ----
    if (t > 0) {
      float v = bfv;
#pragma unroll
      for (int kk = 0; kk < 8; ++kk)
        v += R2[(size_t)(kk * COLS_FC + fc_col) * 20 + fc_row];
      out[(size_t)((t - 1) * 64 + b0 + fc_row) * O_N + cbfc + fc_col] = v;
    }
    // ---- h reduce + tanh + publish (bf16 internal, fp32 hlast) ----
    if (doH) {
      unsigned short* hdst = hx0 + (size_t)(t & 1) * 16 * H_N;
#pragma unroll
      for (int i = 0; i < 2; ++i) {
        const int row = (l >> 3) + 8 * i;
        float v = pb;
#pragma unroll
        for (int kk = 0; kk < 8; ++kk)
          v += R[(size_t)(kk * COLS_H + hr_col) * 20 + row];
        const float hv = tanhf(v);
        hdst[(size_t)row * H_N + cbh + hr_col] = f2bf(hv);
        if (t == T_N - 1) hlast[(size_t)(b0 + row) * H_N + cbh + hr_col] = hv;
      }
      __threadfence();     // drain this thread's h stores to device scope
      __syncthreads();     // S2b: all threads' stores drained before signaling
      if (tid == 0)
        __hip_atomic_store(&flg[m], (unsigned int)(t + 1),
                           __ATOMIC_RELEASE, __HIP_MEMORY_SCOPE_AGENT);
      if (tid < NMEM) {
        while (__hip_atomic_load(&flg[tid], __ATOMIC_RELAXED,
                                 __HIP_MEMORY_SCOPE_AGENT) < (unsigned int)(t + 1))
          __builtin_amdgcn_s_sleep(2);
      }
    }
    __syncthreads();  // S3: barrier result visible to whole block
    __threadfence();  // acquire: invalidate caches before re-reading hx next iter
  }
}

extern "C" void kernel_launch(void* const* d_in, const int* in_sizes, int n_in,
                              void* d_out, int out_size, void* d_ws, size_t ws_size,
                              hipStream_t stream) {
  const float* x   = (const float*)d_in[0];
  const float* hid = (const float*)d_in[1];
  const float* Wih = (const float*)d_in[2];
  const float* Whh = (const float*)d_in[3];
  const float* bih = (const float*)d_in[4];
  const float* bhh = (const float*)d_in[5];
  const float* Wfc = (const float*)d_in[6];
  const float* bfc = (const float*)d_in[7];

  float* out   = (float*)d_out;                      // fp32 [T*B][O]
  float* hlast = out + (size_t)32768 * 512;          // fp32 [B][H]

  unsigned int*   flags = (unsigned int*)d_ws;       // 1 KB
  unsigned short* hx    = (unsigned short*)((char*)d_ws + 1024);  // 256 KB

  hipMemsetAsync(flags, 0, 1024, stream);
  rnn_fused<<<64, NTHR, 0, stream>>>(x, hid, Wih, Whh, bih, bhh, Wfc, bfc,
                                     out, hlast, hx, flags);
}

// Round 4
// 1794.659 us; speedup vs baseline: 6.2380x; 6.2380x over previous
//
#include <hip/hip_runtime.h>

typedef __attribute__((ext_vector_type(8))) short bf16x8;
typedef __attribute__((ext_vector_type(4))) float f32x4;

#define T_N 512
#define I_N 512
#define H_N 1024
#define O_N 512
#define NMEM 16          // blocks per cluster
#define NTHR 512
#define COLS_H 64        // h-cols per block
#define COLS_FC 32       // out-cols per block
#define KW 192           // recurrence K-slice per wave (8 waves * 192 = 1536)
#define KWFC 128         // FC K-slice per wave (8 * 128 = 1024)
#define AP_STRIDE 1544   // A-panel row stride (1536 + 8 pad)
#define RST 21           // reduce-buffer inner stride (21 coprime 32 -> conflict-free col reads)

__device__ __forceinline__ unsigned short f2bf(float f) {
  unsigned int u = __float_as_uint(f);
  u += 0x7fffu + ((u >> 16) & 1u);
  return (unsigned short)(u >> 16);
}
__device__ __forceinline__ bf16x8 cvt8f(const float* __restrict__ p) {
  float4 a = *(const float4*)p;
  float4 b = *(const float4*)(p + 4);
  bf16x8 r;
  r[0] = (short)f2bf(a.x); r[1] = (short)f2bf(a.y);
  r[2] = (short)f2bf(a.z); r[3] = (short)f2bf(a.w);
  r[4] = (short)f2bf(b.x); r[5] = (short)f2bf(b.y);
  r[6] = (short)f2bf(b.z); r[7] = (short)f2bf(b.w);
  return r;
}

// ---- per-access coherent (memory-side / IF$) ops: bypass L1+L2, NO cache flushes ----
__device__ __forceinline__ void coh_store_b32(unsigned int* p, unsigned int v) {
  asm volatile("global_store_dword %0, %1, off sc0 sc1" :: "v"(p), "v"(v) : "memory");
}
__device__ __forceinline__ unsigned int coh_load_b32(const unsigned int* p) {
  unsigned int r;
  asm volatile("global_load_dword %0, %1, off sc0 sc1\n\t"
               "s_waitcnt vmcnt(0)" : "=v"(r) : "v"(p) : "memory");
  return r;
}

// Fused persistent RNN. Grid: 64 blocks = 4 clusters x 16 members, 512 thr (8 waves).
// Per step: h_t = tanh([h_{t-1}|x_t] @ [Whh;Wih]^T + b); FC(t-1) overlapped into the
// inter-block wait window. h exchange + flags via sc0sc1 coherent accesses only.
__global__ __launch_bounds__(NTHR, 2) void rnn_fused(
    const float* __restrict__ x, const float* __restrict__ hidden,
    const float* __restrict__ Wih, const float* __restrict__ Whh,
    const float* __restrict__ bih, const float* __restrict__ bhh,
    const float* __restrict__ Wfc, const float* __restrict__ bfc,
    float* __restrict__ out, float* __restrict__ hlast,
    unsigned short* __restrict__ hx, unsigned int* __restrict__ flags)
{
  __shared__ __align__(16) unsigned short Apan[16 * AP_STRIDE];   // 49408 B
  __shared__ __align__(16) float R [8 * COLS_H  * RST];           // 43008 B
  __shared__ __align__(16) float R2[8 * COLS_FC * RST];           // 21504 B

  const int tid = threadIdx.x;
  const int l = tid & 63, w = tid >> 6;
  const int bid = blockIdx.x;
  const int c = bid & 3;        // cluster (batch group)
  const int m = bid >> 2;       // member 0..15
  const int b0 = c * 16;
  const int cbh = m * COLS_H;
  const int cbfc = m * COLS_FC;
  unsigned short* hxc = hx + (size_t)c * 2 * 16 * H_N;  // [2][16][1024] bf16
  unsigned int* flg = flags + c * 64;

  // ---------------- persistent weight fragments ----------------
  bf16x8 Bh[6][4];
  {
    const int kb0 = w * KW + ((l >> 4) << 3);
#pragma unroll
    for (int kst = 0; kst < 6; ++kst) {
      const int k = kb0 + kst * 32;
#pragma unroll
      for (int f = 0; f < 4; ++f) {
        const int col = cbh + f * 16 + (l & 15);
        const float* src = (k < H_N) ? (Whh + (size_t)col * H_N + k)
                                     : (Wih + (size_t)col * I_N + (k - H_N));
        Bh[kst][f] = cvt8f(src);
      }
    }
  }
  bf16x8 Bf[4][2];
  {
    const int kb0 = w * KWFC + ((l >> 4) << 3);
#pragma unroll
    for (int kst = 0; kst < 4; ++kst)
#pragma unroll
      for (int f = 0; f < 2; ++f) {
        const int col = cbfc + f * 16 + (l & 15);
        Bf[kst][f] = cvt8f(Wfc + (size_t)col * H_N + kb0 + kst * 32);
      }
  }

  // reduce-lane constants: row = 2w + (l>>5), colpair = l&31 (coalesced, conflict-light)
  const int hrow = (w << 1) + (l >> 5);   // 0..15
  const int hcp  = l & 31;                // col pair index
  const float pb0 = bih[cbh + 2 * hcp]     + bhh[cbh + 2 * hcp];
  const float pb1 = bih[cbh + 2 * hcp + 1] + bhh[cbh + 2 * hcp + 1];
  const int frow = hrow;                  // FC: one fp32 per thread
  const int fcol = l & 31;
  const float bfv = bfc[cbfc + fcol];

  const int q0 = tid, q1 = 512 + tid;

  // ---- pre-loop: stage [h_init | x_0], prefetch x_1 ----
#pragma unroll
  for (int i = 0; i < 4; ++i) {
    const int q = i * 512 + tid;
    const int row = q >> 7, hc8 = (q & 127) << 3;
    bf16x8 v = cvt8f(hidden + (size_t)(b0 + row) * H_N + hc8);
    *(bf16x8*)(Apan + row * AP_STRIDE + hc8) = v;
  }
  *(bf16x8*)(Apan + (q0 >> 6) * AP_STRIDE + H_N + ((q0 & 63) << 3)) =
      cvt8f(x + (size_t)(b0 + (q0 >> 6)) * I_N + ((q0 & 63) << 3));
  *(bf16x8*)(Apan + (q1 >> 6) * AP_STRIDE + H_N + ((q1 & 63) << 3)) =
      cvt8f(x + (size_t)(b0 + (q1 >> 6)) * I_N + ((q1 & 63) << 3));
  bf16x8 xr0 = cvt8f(x + (size_t)(64 + b0 + (q0 >> 6)) * I_N + ((q0 & 63) << 3));
  bf16x8 xr1 = cvt8f(x + (size_t)(64 + b0 + (q1 >> 6)) * I_N + ((q1 & 63) << 3));
  __syncthreads();

  for (int t = 0; t < T_N; ++t) {
    // ---- A: recurrence MFMA (critical path), then FC(t-1) MFMA ----
    {
      f32x4 acc[4] = {};
      const int abase = (l & 15) * AP_STRIDE + w * KW + ((l >> 4) << 3);
#pragma unroll
      for (int kst = 0; kst < 6; ++kst) {
        bf16x8 a = *(const bf16x8*)(Apan + abase + kst * 32);
#pragma unroll
        for (int f = 0; f < 4; ++f)
          acc[f] = __builtin_amdgcn_mfma_f32_16x16x32_bf16(a, Bh[kst][f], acc[f], 0, 0, 0);
      }
#pragma unroll
      for (int f = 0; f < 4; ++f)
        *(f32x4*)(R + (size_t)(w * COLS_H + f * 16 + (l & 15)) * RST + ((l >> 4) << 2)) = acc[f];
    }
    if (t > 0) {
      f32x4 afc[2] = {};
      const int ab2 = (l & 15) * AP_STRIDE + w * KWFC + ((l >> 4) << 3);
#pragma unroll
      for (int kst = 0; kst < 4; ++kst) {
        bf16x8 a = *(const bf16x8*)(Apan + ab2 + kst * 32);
        afc[0] = __builtin_amdgcn_mfma_f32_16x16x32_bf16(a, Bf[kst][0], afc[0], 0, 0, 0);
        afc[1] = __builtin_amdgcn_mfma_f32_16x16x32_bf16(a, Bf[kst][1], afc[1], 0, 0, 0);
      }
#pragma unroll
      for (int f = 0; f < 2; ++f)
        *(f32x4*)(R2 + (size_t)(w * COLS_FC + f * 16 + (l & 15)) * RST + ((l >> 4) << 2)) = afc[f];
    }
    __syncthreads();  // S2: partials visible

    // ---- C: h reduce + tanh + coherent publish ----
    {
      float v0 = pb0, v1 = pb1;
#pragma unroll
      for (int kk = 0; kk < 8; ++kk) {
        v0 += R[(size_t)(kk * COLS_H + 2 * hcp)     * RST + hrow];
        v1 += R[(size_t)(kk * COLS_H + 2 * hcp + 1) * RST + hrow];
      }
      const float h0 = tanhf(v0), h1 = tanhf(v1);
      const unsigned int packed =
          (unsigned int)f2bf(h0) | ((unsigned int)f2bf(h1) << 16);
      unsigned int* dst = (unsigned int*)(hxc + (size_t)((t & 1) * 16 + hrow) * H_N + cbh + 2 * hcp);
      coh_store_b32(dst, packed);
      if (t == T_N - 1) {
        float2 fv; fv.x = h0; fv.y = h1;
        *(float2*)(hlast + (size_t)(b0 + hrow) * H_N + cbh + 2 * hcp) = fv;
      }
    }
    asm volatile("s_waitcnt vmcnt(0)" ::: "memory");  // h stores globally visible
    __syncthreads();  // D: all threads drained
    if (tid == 0) coh_store_b32(&flg[m], (unsigned int)(t + 1));

    // ---- E: non-critical work inside the wait window ----
    if (t > 0) {
      float v = bfv;
#pragma unroll
      for (int kk = 0; kk < 8; ++kk)
        v += R2[(size_t)(kk * COLS_FC + fcol) * RST + frow];
      out[(size_t)((t - 1) * 64 + b0 + frow) * O_N + cbfc + fcol] = v;
    }
    if (t + 1 < T_N) {
      *(bf16x8*)(Apan + (q0 >> 6) * AP_STRIDE + H_N + ((q0 & 63) << 3)) = xr0;
      *(bf16x8*)(Apan + (q1 >> 6) * AP_STRIDE + H_N + ((q1 & 63) << 3)) = xr1;
      if (t + 2 < T_N) {
        xr0 = cvt8f(x + (size_t)((t + 2) * 64 + b0 + (q0 >> 6)) * I_N + ((q0 & 63) << 3));
        xr1 = cvt8f(x + (size_t)((t + 2) * 64 + b0 + (q1 >> 6)) * I_N + ((q1 & 63) << 3));
      }
    }

    // ---- H: poll peers (coherent loads, no cache maintenance) ----
    if (tid < NMEM) {
      while (coh_load_b32(&flg[tid]) < (unsigned int)(t + 1))
        __builtin_amdgcn_s_sleep(1);
    }
    __syncthreads();  // I: barrier after poll

    // ---- G: coherent load of h_t, stage into A-panel ----
    {
      const unsigned long long* src =
          (const unsigned long long*)(hxc + (size_t)(t & 1) * 16 * H_N);
      unsigned long long hv[8];
#pragma unroll
      for (int i = 0; i < 8; ++i)
        asm volatile("global_load_dwordx2 %0, %1, off sc0 sc1"
                     : "=v"(hv[i]) : "v"(src + tid + 512 * i) : "memory");
      asm volatile("s_waitcnt vmcnt(0)" ::: "memory");
      __builtin_amdgcn_sched_barrier(0);
#pragma unroll
      for (int i = 0; i < 8; ++i) {
        const int c8 = tid + 512 * i;
        const int row = c8 >> 8, col = (c8 & 255) << 2;
        *(unsigned long long*)(Apan + row * AP_STRIDE + col) = hv[i];
      }
    }
    __syncthreads();  // J: panel ready for next step
  }

  // ---- tail: FC for t = 511 (Apan holds h_511) ----
  {
    f32x4 afc[2] = {};
    const int ab2 = (l & 15) * AP_STRIDE + w * KWFC + ((l >> 4) << 3);
#pragma unroll
    for (int kst = 0; kst < 4; ++kst) {
      bf16x8 a = *(const bf16x8*)(Apan + ab2 + kst * 32);
      afc[0] = __builtin_amdgcn_mfma_f32_16x16x32_bf16(a, Bf[kst][0], afc[0], 0, 0, 0);
      afc[1] = __builtin_amdgcn_mfma_f32_16x16x32_bf16(a, Bf[kst][1], afc[1], 0, 0, 0);
    }
#pragma unroll
    for (int f = 0; f < 2; ++f)
      *(f32x4*)(R2 + (size_t)(w * COLS_FC + f * 16 + (l & 15)) * RST + ((l >> 4) << 2)) = afc[f];
    __syncthreads();
    float v = bfv;
#pragma unroll
    for (int kk = 0; kk < 8; ++kk)
      v += R2[(size_t)(kk * COLS_FC + fcol) * RST + frow];
    out[(size_t)(511 * 64 + b0 + frow) * O_N + cbfc + fcol] = v;
  }
}

extern "C" void kernel_launch(void* const* d_in, const int* in_sizes, int n_in,
                              void* d_out, int out_size, void* d_ws, size_t ws_size,
                              hipStream_t stream) {
  const float* x   = (const float*)d_in[0];
  const float* hid = (const float*)d_in[1];
  const float* Wih = (const float*)d_in[2];
  const float* Whh = (const float*)d_in[3];
  const float* bih = (const float*)d_in[4];
  const float* bhh = (const float*)d_in[5];
  const float* Wfc = (const float*)d_in[6];
  const float* bfc = (const float*)d_in[7];

  float* out   = (float*)d_out;                      // fp32 [T*B][O]
  float* hlast = out + (size_t)32768 * 512;          // fp32 [B][H]

  unsigned int*   flags = (unsigned int*)d_ws;       // 1 KB (4 clusters x 64)
  unsigned short* hx    = (unsigned short*)((char*)d_ws + 1024);  // 256 KB

  hipMemsetAsync(flags, 0, 1024, stream);
  rnn_fused<<<64, NTHR, 0, stream>>>(x, hid, Wih, Whh, bih, bhh, Wfc, bfc,
                                     out, hlast, hx, flags);
}